// Round 1
// baseline (204.011 us; speedup 1.0000x reference)
//
#include <hip/hip_runtime.h>

// Paged KV-cache scatter write (float32).
//   kv_pages: (4096, 16, 16, 128)  -> out (full copy + scatter)
//   new_k, new_v: (8192, 8, 128)
//   t_pages, t_slots: (8192,) int32
// Semantics: out[p,s,0::2,:] = new_k[i]; out[p,s,1::2,:] = new_v[i]
// with numpy last-write-wins on duplicate (p,s) and mode='drop' bounds.

#define NUM_PAGES 4096
#define PAGE_SIZE 16
#define KV_HEADS 8
#define HEAD_SIZE 128
#define N_TOKENS 8192
#define NUM_ROWS (NUM_PAGES * PAGE_SIZE)       // 65536 (page,slot) rows
#define ROW_F4 (2 * KV_HEADS * HEAD_SIZE / 4)  // 512 float4 per row (8 KiB)

__global__ void kv_winners_kernel(const int* __restrict__ t_pages,
                                  const int* __restrict__ t_slots,
                                  int* __restrict__ winner) {
    int i = blockIdx.x * blockDim.x + threadIdx.x;
    if (i >= N_TOKENS) return;
    int p = t_pages[i];
    int s = t_slots[i];
    // mode='drop': out-of-range indices are ignored
    if ((unsigned)p < (unsigned)NUM_PAGES && (unsigned)s < (unsigned)PAGE_SIZE) {
        atomicMax(&winner[p * PAGE_SIZE + s], i);   // last token index wins
    }
}

__global__ void kv_write_kernel(const float4* __restrict__ kv_pages,
                                const float* __restrict__ new_k,
                                const float* __restrict__ new_v,
                                const int* __restrict__ winner,
                                float4* __restrict__ out) {
    const int row = blockIdx.x;                      // page*16 + slot
    const size_t base4 = (size_t)row * ROW_F4;
    const int w = winner[row];                       // uniform per block
    if (w < 0) {
        // untouched row: straight copy
        #pragma unroll
        for (int t = threadIdx.x; t < ROW_F4; t += 256) {
            out[base4 + t] = kv_pages[base4 + t];
        }
    } else {
        // overwritten row: interleave new_k (even heads) / new_v (odd heads)
        #pragma unroll
        for (int t = threadIdx.x; t < ROW_F4; t += 256) {
            int head = t >> 5;                       // 32 float4 per head
            int d4   = t & 31;
            const float* src = (head & 1) ? new_v : new_k;
            size_t off = ((size_t)w * KV_HEADS + (head >> 1)) * HEAD_SIZE + d4 * 4;
            out[base4 + t] = *reinterpret_cast<const float4*>(src + off);
        }
    }
}

extern "C" void kernel_launch(void* const* d_in, const int* in_sizes, int n_in,
                              void* d_out, int out_size, void* d_ws, size_t ws_size,
                              hipStream_t stream) {
    const float* kv_pages = (const float*)d_in[0];
    const float* new_k    = (const float*)d_in[1];
    const float* new_v    = (const float*)d_in[2];
    const int*   t_pages  = (const int*)d_in[3];
    const int*   t_slots  = (const int*)d_in[4];
    float*       out      = (float*)d_out;
    int*         winner   = (int*)d_ws;             // 65536 ints = 256 KiB

    // winner[row] = -1 (0xFFFFFFFF) for "untouched"
    hipMemsetAsync(winner, 0xFF, NUM_ROWS * sizeof(int), stream);

    kv_winners_kernel<<<(N_TOKENS + 255) / 256, 256, 0, stream>>>(t_pages, t_slots, winner);

    kv_write_kernel<<<NUM_ROWS, 256, 0, stream>>>(
        (const float4*)kv_pages, new_k, new_v, winner, (float4*)out);
}

// Round 3
// 199.328 us; speedup vs baseline: 1.0235x; 1.0235x over previous
//
#include <hip/hip_runtime.h>

// Paged KV-cache scatter write (float32).
//   kv_pages: (4096, 16, 16, 128)  -> out (full copy + scatter)
//   new_k, new_v: (8192, 8, 128)
//   t_pages, t_slots: (8192,) int32
// Semantics: out[p,s,0::2,:] = new_k[i]; out[p,s,1::2,:] = new_v[i]
// with numpy last-write-wins on duplicate (p,s) and mode='drop' bounds.
//
// Structure: winner pass (atomicMax of token idx per row) resolves duplicate
// (page,slot) deterministically, then one fused copy-or-scatter streaming pass.

#define NUM_PAGES 4096
#define PAGE_SIZE 16
#define KV_HEADS 8
#define HEAD_SIZE 128
#define N_TOKENS 8192
#define NUM_ROWS (NUM_PAGES * PAGE_SIZE)       // 65536 (page,slot) rows
#define ROW_F4 (2 * KV_HEADS * HEAD_SIZE / 4)  // 512 float4 per row (8 KiB)
#define ROWS_PER_BLOCK 8                       // 64 KiB per block

// Native vector type — __builtin_nontemporal_* requires a real vector type,
// not HIP's HIP_vector_type<float,4> class.
typedef float f32x4 __attribute__((ext_vector_type(4)));

__global__ void kv_winners_kernel(const int* __restrict__ t_pages,
                                  const int* __restrict__ t_slots,
                                  int* __restrict__ winner) {
    int i = blockIdx.x * blockDim.x + threadIdx.x;
    if (i >= N_TOKENS) return;
    int p = t_pages[i];
    int s = t_slots[i];
    // mode='drop': out-of-range indices are ignored
    if ((unsigned)p < (unsigned)NUM_PAGES && (unsigned)s < (unsigned)PAGE_SIZE) {
        atomicMax(&winner[p * PAGE_SIZE + s], i);   // last token index wins
    }
}

__global__ __launch_bounds__(256)
void kv_write_kernel(const f32x4* __restrict__ kv_pages,
                     const float* __restrict__ new_k,
                     const float* __restrict__ new_v,
                     const int* __restrict__ winner,
                     f32x4* __restrict__ out) {
    const int row0 = blockIdx.x * ROWS_PER_BLOCK;

    // Pre-load all winners for this block (uniform, scalar-loadable) so the
    // branch per row is resolved early and loads can issue back-to-back.
    int w[ROWS_PER_BLOCK];
    #pragma unroll
    for (int r = 0; r < ROWS_PER_BLOCK; ++r) w[r] = winner[row0 + r];

    #pragma unroll
    for (int r = 0; r < ROWS_PER_BLOCK; ++r) {
        const int row = row0 + r;
        const size_t base4 = (size_t)row * ROW_F4;
        if (w[r] < 0) {
            // untouched row: straight streaming copy (read-once, write-once)
            #pragma unroll
            for (int t = threadIdx.x; t < ROW_F4; t += 256) {
                f32x4 v = __builtin_nontemporal_load(&kv_pages[base4 + t]);
                __builtin_nontemporal_store(v, &out[base4 + t]);
            }
        } else {
            // overwritten row: interleave new_k (even heads) / new_v (odd heads)
            const int wi = w[r];
            #pragma unroll
            for (int t = threadIdx.x; t < ROW_F4; t += 256) {
                int head = t >> 5;                       // 32 float4 per head
                int d4   = t & 31;
                const float* src = (head & 1) ? new_v : new_k;
                size_t off = ((size_t)wi * KV_HEADS + (head >> 1)) * HEAD_SIZE + d4 * 4;
                f32x4 v = *reinterpret_cast<const f32x4*>(src + off);
                __builtin_nontemporal_store(v, &out[base4 + t]);
            }
        }
    }
}

extern "C" void kernel_launch(void* const* d_in, const int* in_sizes, int n_in,
                              void* d_out, int out_size, void* d_ws, size_t ws_size,
                              hipStream_t stream) {
    const float* kv_pages = (const float*)d_in[0];
    const float* new_k    = (const float*)d_in[1];
    const float* new_v    = (const float*)d_in[2];
    const int*   t_pages  = (const int*)d_in[3];
    const int*   t_slots  = (const int*)d_in[4];
    float*       out      = (float*)d_out;
    int*         winner   = (int*)d_ws;             // 65536 ints = 256 KiB

    // winner[row] = -1 (0xFFFFFFFF) for "untouched"
    (void)hipMemsetAsync(winner, 0xFF, NUM_ROWS * sizeof(int), stream);

    kv_winners_kernel<<<(N_TOKENS + 255) / 256, 256, 0, stream>>>(t_pages, t_slots, winner);

    kv_write_kernel<<<NUM_ROWS / ROWS_PER_BLOCK, 256, 0, stream>>>(
        (const f32x4*)kv_pages, new_k, new_v, winner, (f32x4*)out);
}